// Round 18
// baseline (377.913 us; speedup 1.0000x reference)
//
#include <hip/hip_runtime.h>
#include <math.h>

typedef __attribute__((ext_vector_type(8))) __bf16 bf16x8;
typedef __attribute__((ext_vector_type(4))) float f32x4;

#define NBATCH 8
#define SEQ    1024
#define NHEAD  16
#define DHEAD  64
#define HID    1024
#define MLPD   4096

static __device__ __forceinline__ unsigned short f2bf(float f) {
  unsigned int u = __float_as_uint(f);
  u += 0x7fffu + ((u >> 16) & 1u);
  return (unsigned short)(u >> 16);
}

// async global->LDS, 16B per lane; LDS dest is wave-uniform base + lane*16
static __device__ __forceinline__ void gload_lds16(const unsigned short* g,
                                                   unsigned short* l) {
  __builtin_amdgcn_global_load_lds(
      (const __attribute__((address_space(1))) unsigned int*)g,
      (__attribute__((address_space(3))) unsigned int*)l, 16, 0, 0);
}

// exact tanh-gelu via __expf: tanh(z) = sign(z)*(1-e^{-2|z|})/(1+e^{-2|z|})
static __device__ __forceinline__ float gelu_fast(float v) {
  const float z = 0.7978845608028654f * (v + 0.044715f * v * v * v);
  const float e = __expf(-2.0f * fabsf(z));
  float th = (1.0f - e) / (1.0f + e);
  th = copysignf(th, z);
  return 0.5f * v * (1.0f + th);
}

#define MFMA16(a, b, c) __builtin_amdgcn_mfma_f32_16x16x32_bf16(a, b, c, 0, 0, 0)

// ---------- merged weight prep: 6 transposes (f32 RxC -> bf16 CxR) + bias pack ----------
__global__ __launch_bounds__(256) void k_prep(const float* __restrict__ wq,
                                              const float* __restrict__ wk,
                                              const float* __restrict__ wv,
                                              const float* __restrict__ wo,
                                              const float* __restrict__ w1,
                                              const float* __restrict__ w2,
                                              const float* __restrict__ bq,
                                              const float* __restrict__ bk,
                                              const float* __restrict__ bv,
                                              unsigned short* __restrict__ qkvT,
                                              unsigned short* __restrict__ woT,
                                              unsigned short* __restrict__ w1T,
                                              unsigned short* __restrict__ w2T,
                                              float* __restrict__ bqkv) {
  __shared__ float t[32][33];
  const int b = blockIdx.x;
  const float* in;
  unsigned short* out;
  int R, C, ti;
  if (b < 4096) {
    const int m = b >> 10;
    ti = b & 1023; R = 1024; C = 1024;
    in  = (m == 0) ? wq : (m == 1) ? wk : (m == 2) ? wv : wo;
    out = (m == 3) ? woT : qkvT + (size_t)m * 1024 * 1024;
  } else if (b < 8192) {
    ti = b - 4096; R = 1024; C = 4096; in = w1; out = w1T;
  } else if (b < 12288) {
    ti = b - 8192; R = 4096; C = 1024; in = w2; out = w2T;
  } else {
    const int i = (b - 12288) * 256 + threadIdx.x;
    if (i < 3 * HID)
      bqkv[i] = (i < HID) ? bq[i] : (i < 2 * HID ? bk[i - HID] : bv[i - 2 * HID]);
    return;
  }
  const int tpr = C >> 5;
  const int c0 = (ti % tpr) * 32, r0 = (ti / tpr) * 32;
  const int tx = threadIdx.x & 31, ty = threadIdx.x >> 5;
#pragma unroll
  for (int j = 0; j < 4; ++j)
    t[ty + j * 8][tx] = in[(size_t)(r0 + ty + j * 8) * C + c0 + tx];
  __syncthreads();
#pragma unroll
  for (int j = 0; j < 4; ++j)
    out[(size_t)(c0 + ty + j * 8) * R + r0 + tx] = f2bf(t[tx][ty + j * 8]);
}

// ---------- layernorm: f32 row (1024) -> bf16 row ----------
__global__ __launch_bounds__(256) void k_ln(const float* __restrict__ x,
                                            const float* __restrict__ gw,
                                            const float* __restrict__ bw,
                                            unsigned short* __restrict__ y) {
  __shared__ float red[2][4];
  const int row = blockIdx.x;
  const int tid = threadIdx.x;
  const float4 v = ((const float4*)(x + (size_t)row * HID))[tid];
  float sum = v.x + v.y + v.z + v.w;
  float sq  = v.x * v.x + v.y * v.y + v.z * v.z + v.w * v.w;
#pragma unroll
  for (int off = 32; off >= 1; off >>= 1) {
    sum += __shfl_xor(sum, off);
    sq  += __shfl_xor(sq, off);
  }
  if ((tid & 63) == 0) { red[0][tid >> 6] = sum; red[1][tid >> 6] = sq; }
  __syncthreads();
  sum = red[0][0] + red[0][1] + red[0][2] + red[0][3];
  sq  = red[1][0] + red[1][1] + red[1][2] + red[1][3];
  const float mu  = sum * (1.0f / HID);
  const float var = sq * (1.0f / HID) - mu * mu;
  const float rs  = rsqrtf(var + 1e-5f);
  const float4 g4 = ((const float4*)gw)[tid];
  const float4 b4 = ((const float4*)bw)[tid];
  ushort4 ov;
  ov.x = f2bf((v.x - mu) * rs * g4.x + b4.x);
  ov.y = f2bf((v.y - mu) * rs * g4.y + b4.y);
  ov.z = f2bf((v.z - mu) * rs * g4.z + b4.z);
  ov.w = f2bf((v.w - mu) * rs * g4.w + b4.w);
  ((ushort4*)(y + (size_t)row * HID))[tid] = ov;
}

// ---------- NT GEMM A: 128x128, BK=32, 32KB LDS -> 3+ blocks/CU (K=1024) ----------
// 8 waves (512 thr), per-wave out 64x32, acc[4][2]. Per K-tile: gate
// {vmcnt(0); s_barrier}; 2 DMA calls for t+1; 6 ds_reads; 8 MFMA. Gate stalls
// overlap across >=3 resident blocks (occupancy mechanism, confirmed R16).
template <int EPI>
__global__ __launch_bounds__(512, 6) void k_g32(const unsigned short* __restrict__ A,
                                                const unsigned short* __restrict__ BT,
                                                const float* __restrict__ bias,
                                                const float* __restrict__ res,
                                                void* __restrict__ Cout,
                                                int M, int N, int K) {
  constexpr int ASZ = 128 * 32;        // 8KB per A buffer
  constexpr int BSZ = 128 * 32;        // 8KB per B buffer
  constexpr int NF  = 2;
  constexpr int NCW = 32;
  __shared__ unsigned short sh[2 * ASZ + 2 * BSZ];   // 32KB

  const int tid  = threadIdx.x;
  const int lane = tid & 63;
  const int w    = tid >> 6;
  const int wr   = w >> 2, wc = w & 3;
  const int l15  = lane & 15, g = lane >> 4;

  const int gx = gridDim.x;
  const int nwg = gx * gridDim.y;
  int lid = blockIdx.y * gx + blockIdx.x;
  lid = (lid & 7) * (nwg >> 3) + (lid >> 3);
  const int m0 = (lid / gx) * 128, n0 = (lid % gx) * 128;

  f32x4 acc[4][NF] = {};

  // staging: wave w covers 16 rows of each 128-row tile; lane -> row lane>>2,
  // chunk (lane&3)^((lane>>3)&3) = chunk ^ ((row>>1)&3) (64B-row swizzle)
  const int srow4 = lane >> 2;
  const int schk  = (lane & 3) ^ ((lane >> 3) & 3);
  const unsigned short* pA = A  + (size_t)(m0 + w * 16 + srow4) * K + schk * 8;
  const unsigned short* pB = BT + (size_t)(n0 + w * 16 + srow4) * K + schk * 8;
  unsigned short* shB = sh + 2 * ASZ;

#define STAGE32(buf_, kk)                                                 \
  do {                                                                    \
    gload_lds16(pA + (kk), sh  + (buf_) * ASZ + (w * 16) * 32);           \
    gload_lds16(pB + (kk), shB + (buf_) * BSZ + (w * 16) * 32);           \
  } while (0)

  const int fko = (g ^ ((l15 >> 1) & 3)) * 8;
  const int aRowBase = wr * 64 + l15;
  const int bRowBase = wc * NCW + l15;

  const int NT = K >> 5;

  STAGE32(0, 0);
  int buf = 0;
  for (int t = 0; t < NT; ++t) {
    const unsigned short* shAb = sh + buf * ASZ;
    const unsigned short* shBb = shB + buf * BSZ;

    asm volatile("s_waitcnt vmcnt(0)" ::: "memory");
    __builtin_amdgcn_sched_barrier(0);
    __builtin_amdgcn_s_barrier();
    if (t + 1 < NT) STAGE32(buf ^ 1, (t + 1) * 32);

    bf16x8 bfr[NF];
#pragma unroll
    for (int n = 0; n < NF; ++n)
      bfr[n] = *(const bf16x8*)(shBb + (bRowBase + n * 16) * 32 + fko);
    bf16x8 afr[4];
#pragma unroll
    for (int m = 0; m < 4; ++m)
      afr[m] = *(const bf16x8*)(shAb + (aRowBase + m * 16) * 32 + fko);
    __builtin_amdgcn_sched_barrier(0);

#pragma unroll
    for (int m = 0; m < 4; ++m)
#pragma unroll
      for (int n = 0; n < NF; ++n)
        acc[m][n] = MFMA16(afr[m], bfr[n], acc[m][n]);
    buf ^= 1;
  }
#undef STAGE32

  if constexpr (EPI == 2) {
#pragma unroll
    for (int m = 0; m < 4; ++m) {
#pragma unroll
      for (int n = 0; n < NF; ++n) {
        const int col = n0 + wc * NCW + n * 16 + l15;
        const float bc = bias[col];
#pragma unroll
        for (int r = 0; r < 4; ++r) {
          const int row = m0 + wr * 64 + m * 16 + g * 4 + r;
          const size_t idx = (size_t)row * N + col;
          ((float*)Cout)[idx] = acc[m][n][r] + bc + res[idx];
        }
      }
    }
  } else {
    // bf16 out via per-wave 64x32 LDS tile (8 x 4KB = 32KB, exact fit)
    __builtin_amdgcn_s_barrier();
    unsigned short* ep = sh + w * (64 * NCW);
#pragma unroll
    for (int m = 0; m < 4; ++m) {
#pragma unroll
      for (int n = 0; n < NF; ++n) {
        const float bc = bias[n0 + wc * NCW + n * 16 + l15];
#pragma unroll
        for (int r = 0; r < 4; ++r) {
          float v = acc[m][n][r] + bc;
          if constexpr (EPI == 1) v = gelu_fast(v);
          ep[(m * 16 + g * 4 + r) * NCW + n * 16 + l15] = f2bf(v);
        }
      }
    }
#pragma unroll
    for (int j = 0; j < 4; ++j) {
      const int t = lane + j * 64;
      const int row = t >> 2, colb = (t & 3) * 8;
      const uint4 vv = *(const uint4*)(ep + row * NCW + colb);
      unsigned short* outp = (unsigned short*)Cout +
          (size_t)(m0 + wr * 64 + row) * N + n0 + wc * NCW + colb;
      *(uint4*)outp = vv;
    }
  }
}

// ---------- NT GEMM B: 256x128, BK=64, 96KB LDS (for K=4096) ----------
template <int EPI>
__global__ __launch_bounds__(512, 2) void k_g64(const unsigned short* __restrict__ A,
                                                const unsigned short* __restrict__ BT,
                                                const float* __restrict__ bias,
                                                const float* __restrict__ res,
                                                void* __restrict__ Cout,
                                                int M, int N, int K) {
  constexpr int BN  = 128;
  constexpr int ASZ = 256 * 64;
  constexpr int BSZ = BN * 64;
  constexpr int NF  = 2;
  constexpr int NCW = 32;
  __shared__ unsigned short sh[2 * ASZ + 2 * BSZ];   // 96KB

  const int tid  = threadIdx.x;
  const int lane = tid & 63;
  const int w    = tid >> 6;
  const int wr   = w >> 2, wc = w & 3;
  const int l15  = lane & 15, g = lane >> 4;

  const int gx = gridDim.x;
  const int nwg = gx * gridDim.y;
  int lid = blockIdx.y * gx + blockIdx.x;
  lid = (lid & 7) * (nwg >> 3) + (lid >> 3);
  const int m0 = (lid / gx) * 256, n0 = (lid % gx) * BN;

  f32x4 acc[8][NF] = {};

  const int srow  = w * 8 + (lane >> 3);
  const int scolb = ((lane & 7) * 16) ^ (((lane >> 3) & 7) << 4);
  const unsigned short* pA = A  + (size_t)(m0 + srow) * K + (scolb >> 1);
  const unsigned short* pB = BT + (size_t)(n0 + srow) * K + (scolb >> 1);
  unsigned short* shB = sh + 2 * ASZ;

#define STAGE64(buf_, kk)                                                   \
  do {                                                                      \
    _Pragma("unroll") for (int c = 0; c < 4; ++c)                           \
      gload_lds16(pA + (size_t)c * 64 * K + (kk),                           \
                  sh + (buf_) * ASZ + (c * 64 + w * 8) * 64);               \
    _Pragma("unroll") for (int c = 0; c < BN / 64; ++c)                     \
      gload_lds16(pB + (size_t)c * 64 * K + (kk),                           \
                  shB + (buf_) * BSZ + (c * 64 + w * 8) * 64);              \
  } while (0)

  const int fmask = (l15 & 7) << 4;
  const int bo0 = ((0 * 64) + g * 16) ^ fmask;
  const int bo1 = ((1 * 64) + g * 16) ^ fmask;
  const int aRowBase = wr * 128 + l15;
  const int bRowBase = wc * NCW + l15;

  const int NT = K >> 6;

  STAGE64(0, 0);
  int buf = 0;
  for (int t = 0; t < NT; ++t) {
    const unsigned short* shAb = sh + buf * ASZ;
    const unsigned short* shBb = shB + buf * BSZ;

    asm volatile("s_waitcnt vmcnt(0)" ::: "memory");
    __builtin_amdgcn_sched_barrier(0);
    __builtin_amdgcn_s_barrier();
    if (t + 1 < NT) STAGE64(buf ^ 1, (t + 1) * 64);

    bf16x8 bfr[NF][2];
#pragma unroll
    for (int n = 0; n < NF; ++n) {
      const int br = (bRowBase + n * 16) * 64;
      bfr[n][0] = *(const bf16x8*)(shBb + br + (bo0 >> 1));
      bfr[n][1] = *(const bf16x8*)(shBb + br + (bo1 >> 1));
    }
    bf16x8 afr[8][2];
#pragma unroll
    for (int m = 0; m < 8; ++m) {
      const int ar = (aRowBase + m * 16) * 64;
      afr[m][0] = *(const bf16x8*)(shAb + ar + (bo0 >> 1));
      afr[m][1] = *(const bf16x8*)(shAb + ar + (bo1 >> 1));
    }
    __builtin_amdgcn_sched_barrier(0);

#pragma unroll
    for (int p = 0; p < 4; ++p) {
#pragma unroll
      for (int n = 0; n < NF; ++n) {
        acc[2 * p][n]     = MFMA16(afr[2 * p][0],     bfr[n][0], acc[2 * p][n]);
        acc[2 * p][n]     = MFMA16(afr[2 * p][1],     bfr[n][1], acc[2 * p][n]);
        acc[2 * p + 1][n] = MFMA16(afr[2 * p + 1][0], bfr[n][0], acc[2 * p + 1][n]);
        acc[2 * p + 1][n] = MFMA16(afr[2 * p + 1][1], bfr[n][1], acc[2 * p + 1][n]);
      }
    }
    buf ^= 1;
  }
#undef STAGE64

  if constexpr (EPI == 2) {
#pragma unroll
    for (int m = 0; m < 8; ++m) {
#pragma unroll
      for (int n = 0; n < NF; ++n) {
        const int col = n0 + wc * NCW + n * 16 + l15;
        const float bc = bias[col];
#pragma unroll
        for (int r = 0; r < 4; ++r) {
          const int row = m0 + wr * 128 + m * 16 + g * 4 + r;
          const size_t idx = (size_t)row * N + col;
          ((float*)Cout)[idx] = acc[m][n][r] + bc + res[idx];
        }
      }
    }
  } else {
    __builtin_amdgcn_s_barrier();
    unsigned short* ep = sh + w * (128 * NCW);
#pragma unroll
    for (int m = 0; m < 8; ++m) {
#pragma unroll
      for (int n = 0; n < NF; ++n) {
        const float bc = bias[n0 + wc * NCW + n * 16 + l15];
#pragma unroll
        for (int r = 0; r < 4; ++r) {
          float v = acc[m][n][r] + bc;
          if constexpr (EPI == 1) v = gelu_fast(v);
          ep[(m * 16 + g * 4 + r) * NCW + n * 16 + l15] = f2bf(v);
        }
      }
    }
    constexpr int CPR = NCW / 8;
#pragma unroll
    for (int j = 0; j < NCW / 4; ++j) {
      const int t = lane + j * 64;
      const int row = t / CPR, colb = (t % CPR) * 8;
      const uint4 vv = *(const uint4*)(ep + row * NCW + colb);
      unsigned short* outp = (unsigned short*)Cout +
          (size_t)(m0 + wr * 128 + row) * N + n0 + wc * NCW + colb;
      *(uint4*)outp = vv;
    }
  }
}

// ---------- V transpose: qkv (M x 3072) V-columns -> vT [nh][64][1024] bf16 ----------
__global__ __launch_bounds__(256) void k_vt(const unsigned short* __restrict__ qkv,
                                            unsigned short* __restrict__ vT) {
  __shared__ unsigned short t[64][72];
  const int nh = blockIdx.y;
  const int nb = nh >> 4, h = nh & 15;
  const int l0 = blockIdx.x * 64;
  const int tx = threadIdx.x & 7;
  const int ty = threadIdx.x >> 3;
  const unsigned short* src = qkv + (size_t)(nb * SEQ + l0) * 3072 + 2048 + h * DHEAD;
#pragma unroll
  for (int j = 0; j < 2; ++j)
    *(uint4*)(&t[ty + j * 32][tx * 8]) =
        *(const uint4*)(&src[(size_t)(ty + j * 32) * 3072 + tx * 8]);
  __syncthreads();
  unsigned short* dst = vT + (size_t)nh * DHEAD * SEQ + l0;
#pragma unroll
  for (int j = 0; j < 2; ++j) {
    const int d = ty + j * 32;
    ushort4 a, b;
    a.x = t[tx * 8 + 0][d]; a.y = t[tx * 8 + 1][d];
    a.z = t[tx * 8 + 2][d]; a.w = t[tx * 8 + 3][d];
    b.x = t[tx * 8 + 4][d]; b.y = t[tx * 8 + 5][d];
    b.z = t[tx * 8 + 6][d]; b.w = t[tx * 8 + 7][d];
    *(ushort4*)(&dst[(size_t)d * SEQ + tx * 8])     = a;
    *(ushort4*)(&dst[(size_t)d * SEQ + tx * 8 + 4]) = b;
  }
}

// ---------- flash attention, LDS-staged K/V, swapped QK^T ----------
#define SOFTMAX_GROUP(S, gq)                                                       \
  {                                                                                \
    float mx = -INFINITY;                                                          \
    _Pragma("unroll") for (int c = 0; c < 4; ++c)                                  \
      _Pragma("unroll") for (int r = 0; r < 4; ++r)                                \
        mx = fmaxf(mx, S[c][r]);                                                   \
    mx = fmaxf(mx, __shfl_xor(mx, 16));                                            \
    mx = fmaxf(mx, __shfl_xor(mx, 32));                                            \
    const float mnew = fmaxf(m_run[gq], mx);                                       \
    const float sc = __expf(0.125f * (m_run[gq] - mnew));                          \
    m_run[gq] = mnew;                                                              \
    float ts = 0.0f;                                                               \
    _Pragma("unroll") for (int c = 0; c < 4; ++c) {                                \
      const float p0 = __expf(0.125f * (S[c][0] - mnew));                          \
      const float p1 = __expf(0.125f * (S[c][1] - mnew));                          \
      const float p2 = __expf(0.125f * (S[c][2] - mnew));                          \
      const float p3 = __expf(0.125f * (S[c][3] - mnew));                          \
      ts += (p0 + p1) + (p2 + p3);                                                 \
      const unsigned int lo = (unsigned int)f2bf(p0) | ((unsigned int)f2bf(p1) << 16); \
      const unsigned int hi = (unsigned int)f2bf(p2) | ((unsigned int)f2bf(p3) << 16); \
      *(uint2*)(&P_lds[w][((gq) * 16 + l15) * 72 + c * 16 + g * 4]) = make_uint2(lo, hi); \
    }                                                                              \
    ts += __shfl_xor(ts, 16);                                                      \
    ts += __shfl_xor(ts, 32);                                                      \
    s_run[gq] = s_run[gq] * sc + ts;                                               \
    const float scr0 = __shfl(sc, g * 4 + 0), scr1 = __shfl(sc, g * 4 + 1);        \
    const float scr2 = __shfl(sc, g * 4 + 2), scr3 = __shfl(sc, g * 4 + 3);        \
    _Pragma("unroll") for (int dt = 0; dt < 4; ++dt) {                             \
      o[gq][dt][0] *= scr0; o[gq][dt][1] *= scr1;                                  \
      o[gq][dt][2] *= scr2; o[gq][dt][3] *= scr3;                                  \
    }                                                                              \
  }

__global__ __launch_bounds__(256, 4) void k_attn(const unsigned short* __restrict__ qkv,
                                                 const unsigned short* __restrict__ vT,
                                                 unsigned short* __restrict__ outp) {
  __shared__ unsigned short Ks[64 * 64];
  __shared__ unsigned short Vs[64 * 64];
  __shared__ unsigned short P_lds[4][32 * 72];
  const int tid  = threadIdx.x;
  const int lane = tid & 63;
  const int w    = tid >> 6;
  const int l15  = lane & 15, g = lane >> 4;
  const int nh = blockIdx.y;
  const int nb = nh >> 4, h = nh & 15;
  const int q0 = blockIdx.x * 128 + w * 32;
  const size_t RS = 3 * HID;

  const unsigned short* Qp = qkv + (size_t)(nb * SEQ + q0) * RS + h * DHEAD;
  const unsigned short* Kg = qkv + (size_t)(nb * SEQ) * RS + HID + h * DHEAD;
  const unsigned short* Vg = vT + (size_t)nh * DHEAD * SEQ;

  const int L0 = tid * 32, L1 = L0 + 16;
  const int kr0 = L0 >> 7, kc0 = (L0 & 127) ^ ((kr0 & 7) << 4);
  const int kr1 = L1 >> 7, kc1 = (L1 & 127) ^ ((kr1 & 7) << 4);

  bf16x8 aq[2][2];
#pragma unroll
  for (int gq = 0; gq < 2; ++gq)
#pragma unroll
    for (int t = 0; t < 2; ++t)
      aq[gq][t] = *(const bf16x8*)(&Qp[(size_t)(gq * 16 + l15) * RS + t * 32 + g * 8]);

  f32x4 o[2][4] = {};
  float m_run[2] = {-INFINITY, -INFINITY};
  float s_run[2] = {0.0f, 0.0f};

  uint4 rk0, rk1, rv0, rv1;
  rk0 = *(const uint4*)(Kg + (size_t)kr0 * RS + (kc0 >> 1));
  rk1 = *(const uint4*)(Kg + (size_t)kr1 * RS + (kc1 >> 1));
  rv0 = *(const uint4*)(Vg + (size_t)kr0 * SEQ + (kc0 >> 1));
  rv1 = *(const uint4*)(Vg + (size_t)kr1 * SEQ + (kc1 >> 1));
  *(uint4*)(&Ks[tid * 16])     = rk0;
  *(uint4*)(&Ks[tid * 16 + 8]) = rk1;
  *(uint4*)(&Vs[tid * 16])     = rv0;
  *(uint4*)(&Vs[tid * 16 + 8]) = rv1;
  __syncthreads();

  const int sw = (l15 & 7) << 4;

  for (int t16 = 0; t16 < 16; ++t16) {
    if (t16 < 15) {
      const int kb = (t16 + 1) * 64;
      rk0 = *(const uint4*)(Kg + (size_t)(kb + kr0) * RS + (kc0 >> 1));
      rk1 = *(const uint4*)(Kg + (size_t)(kb + kr1) * RS + (kc1 >> 1));
      rv0 = *(const uint4*)(Vg + (size_t)kr0 * SEQ + kb + (kc0 >> 1));
      rv1 = *(const uint4*)(Vg + (size_t)kr1 * SEQ + kb + (kc1 >> 1));
    }

    f32x4 S0[4], S1[4];
#pragma unroll
    for (int c = 0; c < 4; ++c) {
      const int krow = c * 16 + l15;
      const bf16x8 k0 = *(const bf16x8*)(&Ks[krow * 64 + ((( 0 + g * 16) ^ sw) >> 1)]);
      const bf16x8 k1 = *(const bf16x8*)(&Ks[krow * 64 + (((64 + g * 16) ^ sw) >> 1)]);
      f32x4 a = {};
      a = MFMA16(k0, aq[0][0], a);
      a = MFMA16(k1, aq[0][1], a);
      S0[c] = a;
      f32x4 b = {};
      b = MFMA16(k0, aq[1][0], b);
      b = MFMA16(k1, aq[1][1], b);
      S1[c] = b;
    }

    SOFTMAX_GROUP(S0, 0)
    SOFTMAX_GROUP(S1, 1)

    bf16x8 pa[2][2];
#pragma unroll
    for (int gq = 0; gq < 2; ++gq)
#pragma unroll
      for (int th = 0; th < 2; ++th)
        pa[gq][th] = *(const bf16x8*)(&P_lds[w][(gq * 16 + l15) * 72 + th * 32 + g * 8]);
#pragma unroll
    for (int dt = 0; dt < 4; ++dt) {
      const int vrow = dt * 16 + l15;
      const bf16x8 v0 = *(const bf16x8*)(&Vs[vrow * 64 + ((( 0 + g * 16) ^ sw) >> 1)]);
      const bf16x8 v1 = *(const bf16x8*)(&Vs[vrow * 64 + (((64 + g * 16) ^ sw) >> 1)]);
      o[0][dt] = MFMA16(pa[0][0], v0, o[0][dt]);
      o[0][dt] = MFMA16(pa[0][1], v1, o[0][dt]);
      o[1][dt] = MFMA16(pa[1][0], v0, o[1][dt]);
      o[1][dt] = MFMA16(pa[1][1], v1, o[1][dt]);
    }
    __syncthreads();
    if (t16 < 15) {
      *(uint4*)(&Ks[tid * 16])     = rk0;
      *(uint4*)(&Ks[tid * 16 + 8]) = rk1;
      *(uint4*)(&Vs[tid * 16])     = rv0;
      *(uint4*)(&Vs[tid * 16 + 8]) = rv1;
      __syncthreads();
    }
  }

#pragma unroll
  for (int gq = 0; gq < 2; ++gq) {
    float sr[4];
#pragma unroll
    for (int r = 0; r < 4; ++r) sr[r] = 1.0f / __shfl(s_run[gq], g * 4 + r);
#pragma unroll
    for (int dt = 0; dt < 4; ++dt)
#pragma unroll
      for (int r = 0; r < 4; ++r)
        outp[(size_t)(nb * SEQ + q0 + gq * 16 + g * 4 + r) * HID + h * DHEAD + dt * 16 + l15] =
            f2bf(o[gq][dt][r] * sr[r]);
  }
}

extern "C" void kernel_launch(void* const* d_in, const int* in_sizes, int n_in,
                              void* d_out, int out_size, void* d_ws, size_t ws_size,
                              hipStream_t stream) {
  const float* x    = (const float*)d_in[0];
  const float* ln0g = (const float*)d_in[1];
  const float* ln0b = (const float*)d_in[2];
  const float* wq   = (const float*)d_in[3];
  const float* bq   = (const float*)d_in[4];
  const float* wk   = (const float*)d_in[5];
  const float* bk   = (const float*)d_in[6];
  const float* wv   = (const float*)d_in[7];
  const float* bv   = (const float*)d_in[8];
  const float* wo   = (const float*)d_in[9];
  const float* bo   = (const float*)d_in[10];
  const float* ln1g = (const float*)d_in[11];
  const float* ln1b = (const float*)d_in[12];
  const float* w1   = (const float*)d_in[13];
  const float* b1   = (const float*)d_in[14];
  const float* w2   = (const float*)d_in[15];
  const float* b2   = (const float*)d_in[16];
  float* out = (float*)d_out;

  char* ws = (char*)d_ws;
  unsigned short* qkvT = (unsigned short*)(ws + 0);          // 3072x1024 bf16   (6 MB)
  unsigned short* woT  = (unsigned short*)(ws + 6291456);    // 1024x1024 bf16   (2 MB)
  unsigned short* w1T  = (unsigned short*)(ws + 8388608);    // 4096x1024 bf16   (8 MB)
  unsigned short* w2T  = (unsigned short*)(ws + 16777216);   // 1024x4096 bf16   (8 MB)
  float*          bqkv = (float*)(ws + 25165824);            // 3072 f32
  unsigned short* ybuf = (unsigned short*)(ws + 25178112);   // 8192x1024 bf16   (16 MB)
  unsigned short* qkv  = (unsigned short*)(ws + 41955328);   // 8192x3072 bf16   (48 MB)
  unsigned short* att  = (unsigned short*)(ws + 92286976);   // 8192x1024 bf16   (16 MB)
  unsigned short* hbuf = qkv;   // 8192x4096 bf16 (64 MB) overlays qkv+att (both dead)
  unsigned short* vT   = ybuf;  // 128x64x1024 bf16 (16 MB) overlays ybuf

  const int M = NBATCH * SEQ;  // 8192

  // merged weight prep: ONE launch
  k_prep<<<dim3(12300), 256, 0, stream>>>(wq, wk, wv, wo, w1, w2, bq, bk, bv,
                                          qkvT, woT, w1T, w2T, bqkv);

  // LN0 -> y
  k_ln<<<dim3(M), 256, 0, stream>>>(x, ln0g, ln0b, ybuf);
  // QKV (K=1024): 128x128 tile, 24x64 blocks, 3+ blocks/CU
  k_g32<0><<<dim3(24, 64), 512, 0, stream>>>(ybuf, qkvT, bqkv, nullptr, (void*)qkv, M, 3 * HID, HID);
  // V^T materialization
  k_vt<<<dim3(16, 128), 256, 0, stream>>>(qkv, vT);
  // attention
  k_attn<<<dim3(8, 128), 256, 0, stream>>>(qkv, vT, att);
  // x1 = x + att @ wo + bo (K=1024): 8x64 blocks
  k_g32<2><<<dim3(8, 64), 512, 0, stream>>>(att, woT, bo, x, (void*)out, M, HID, HID);
  // LN1 -> y
  k_ln<<<dim3(M), 256, 0, stream>>>(out, ln1g, ln1b, ybuf);
  // h = gelu(y @ w1 + b1) (K=1024): 32x64 blocks
  k_g32<1><<<dim3(32, 64), 512, 0, stream>>>(ybuf, w1T, b1, nullptr, (void*)hbuf, M, MLPD, HID);
  // out = d_out + h @ w2 + b2 (K=4096): BK=64 kernel
  k_g64<2><<<dim3(8, 32), 512, 0, stream>>>(hbuf, w2T, b2, out, (void*)out, M, HID, MLPD);
}

// Round 19
// 359.912 us; speedup vs baseline: 1.0500x; 1.0500x over previous
//
#include <hip/hip_runtime.h>
#include <math.h>

typedef __attribute__((ext_vector_type(8))) __bf16 bf16x8;
typedef __attribute__((ext_vector_type(4))) float f32x4;

#define NBATCH 8
#define SEQ    1024
#define NHEAD  16
#define DHEAD  64
#define HID    1024
#define MLPD   4096

static __device__ __forceinline__ unsigned short f2bf(float f) {
  unsigned int u = __float_as_uint(f);
  u += 0x7fffu + ((u >> 16) & 1u);
  return (unsigned short)(u >> 16);
}

// async global->LDS, 16B per lane; LDS dest is wave-uniform base + lane*16
static __device__ __forceinline__ void gload_lds16(const unsigned short* g,
                                                   unsigned short* l) {
  __builtin_amdgcn_global_load_lds(
      (const __attribute__((address_space(1))) unsigned int*)g,
      (__attribute__((address_space(3))) unsigned int*)l, 16, 0, 0);
}

// exact tanh-gelu via __expf: tanh(z) = sign(z)*(1-e^{-2|z|})/(1+e^{-2|z|})
static __device__ __forceinline__ float gelu_fast(float v) {
  const float z = 0.7978845608028654f * (v + 0.044715f * v * v * v);
  const float e = __expf(-2.0f * fabsf(z));
  float th = (1.0f - e) / (1.0f + e);
  th = copysignf(th, z);
  return 0.5f * v * (1.0f + th);
}

#define MFMA16(a, b, c) __builtin_amdgcn_mfma_f32_16x16x32_bf16(a, b, c, 0, 0, 0)

// ---------- merged weight prep: 6 transposes (f32 RxC -> bf16 CxR) + bias pack ----------
__global__ __launch_bounds__(256) void k_prep(const float* __restrict__ wq,
                                              const float* __restrict__ wk,
                                              const float* __restrict__ wv,
                                              const float* __restrict__ wo,
                                              const float* __restrict__ w1,
                                              const float* __restrict__ w2,
                                              const float* __restrict__ bq,
                                              const float* __restrict__ bk,
                                              const float* __restrict__ bv,
                                              unsigned short* __restrict__ qkvT,
                                              unsigned short* __restrict__ woT,
                                              unsigned short* __restrict__ w1T,
                                              unsigned short* __restrict__ w2T,
                                              float* __restrict__ bqkv) {
  __shared__ float t[32][33];
  const int b = blockIdx.x;
  const float* in;
  unsigned short* out;
  int R, C, ti;
  if (b < 4096) {
    const int m = b >> 10;
    ti = b & 1023; R = 1024; C = 1024;
    in  = (m == 0) ? wq : (m == 1) ? wk : (m == 2) ? wv : wo;
    out = (m == 3) ? woT : qkvT + (size_t)m * 1024 * 1024;
  } else if (b < 8192) {
    ti = b - 4096; R = 1024; C = 4096; in = w1; out = w1T;
  } else if (b < 12288) {
    ti = b - 8192; R = 4096; C = 1024; in = w2; out = w2T;
  } else {
    const int i = (b - 12288) * 256 + threadIdx.x;
    if (i < 3 * HID)
      bqkv[i] = (i < HID) ? bq[i] : (i < 2 * HID ? bk[i - HID] : bv[i - 2 * HID]);
    return;
  }
  const int tpr = C >> 5;
  const int c0 = (ti % tpr) * 32, r0 = (ti / tpr) * 32;
  const int tx = threadIdx.x & 31, ty = threadIdx.x >> 5;
#pragma unroll
  for (int j = 0; j < 4; ++j)
    t[ty + j * 8][tx] = in[(size_t)(r0 + ty + j * 8) * C + c0 + tx];
  __syncthreads();
#pragma unroll
  for (int j = 0; j < 4; ++j)
    out[(size_t)(c0 + ty + j * 8) * R + r0 + tx] = f2bf(t[tx][ty + j * 8]);
}

// ---------- layernorm: f32 row (1024) -> bf16 row ----------
__global__ __launch_bounds__(256) void k_ln(const float* __restrict__ x,
                                            const float* __restrict__ gw,
                                            const float* __restrict__ bw,
                                            unsigned short* __restrict__ y) {
  __shared__ float red[2][4];
  const int row = blockIdx.x;
  const int tid = threadIdx.x;
  const float4 v = ((const float4*)(x + (size_t)row * HID))[tid];
  float sum = v.x + v.y + v.z + v.w;
  float sq  = v.x * v.x + v.y * v.y + v.z * v.z + v.w * v.w;
#pragma unroll
  for (int off = 32; off >= 1; off >>= 1) {
    sum += __shfl_xor(sum, off);
    sq  += __shfl_xor(sq, off);
  }
  if ((tid & 63) == 0) { red[0][tid >> 6] = sum; red[1][tid >> 6] = sq; }
  __syncthreads();
  sum = red[0][0] + red[0][1] + red[0][2] + red[0][3];
  sq  = red[1][0] + red[1][1] + red[1][2] + red[1][3];
  const float mu  = sum * (1.0f / HID);
  const float var = sq * (1.0f / HID) - mu * mu;
  const float rs  = rsqrtf(var + 1e-5f);
  const float4 g4 = ((const float4*)gw)[tid];
  const float4 b4 = ((const float4*)bw)[tid];
  ushort4 ov;
  ov.x = f2bf((v.x - mu) * rs * g4.x + b4.x);
  ov.y = f2bf((v.y - mu) * rs * g4.y + b4.y);
  ov.z = f2bf((v.z - mu) * rs * g4.z + b4.z);
  ov.w = f2bf((v.w - mu) * rs * g4.w + b4.w);
  ((ushort4*)(y + (size_t)row * HID))[tid] = ov;
}

// ---------- NT GEMM (R15): 256xBN tile, BK=64, free-running, no setprio ----------
template <int EPI, int BN>
__global__ __launch_bounds__(512, 2) void k_gemm(const unsigned short* __restrict__ A,
                                                 const unsigned short* __restrict__ BT,
                                                 const float* __restrict__ bias,
                                                 const float* __restrict__ res,
                                                 void* __restrict__ Cout,
                                                 int M, int N, int K) {
  constexpr int ASZ = 256 * 64;
  constexpr int BSZ = BN * 64;
  constexpr int NF  = BN / 64;
  constexpr int NCW = BN / 4;
  __shared__ unsigned short sh[2 * ASZ + 2 * BSZ];

  const int tid  = threadIdx.x;
  const int lane = tid & 63;
  const int w    = tid >> 6;
  const int wr   = w >> 2, wc = w & 3;
  const int l15  = lane & 15, g = lane >> 4;

  const int gx = gridDim.x;
  const int nwg = gx * gridDim.y;
  int lid = blockIdx.y * gx + blockIdx.x;
  lid = (lid & 7) * (nwg >> 3) + (lid >> 3);
  const int m0 = (lid / gx) * 256, n0 = (lid % gx) * BN;

  f32x4 acc[8][NF] = {};

  const int srow  = w * 8 + (lane >> 3);
  const int scolb = ((lane & 7) * 16) ^ (((lane >> 3) & 7) << 4);
  const unsigned short* pA = A  + (size_t)(m0 + srow) * K + (scolb >> 1);
  const unsigned short* pB = BT + (size_t)(n0 + srow) * K + (scolb >> 1);
  unsigned short* shB = sh + 2 * ASZ;

#define STAGE(buf_, kk)                                                     \
  do {                                                                      \
    _Pragma("unroll") for (int c = 0; c < 4; ++c)                           \
      gload_lds16(pA + (size_t)c * 64 * K + (kk),                           \
                  sh + (buf_) * ASZ + (c * 64 + w * 8) * 64);               \
    _Pragma("unroll") for (int c = 0; c < BN / 64; ++c)                     \
      gload_lds16(pB + (size_t)c * 64 * K + (kk),                           \
                  shB + (buf_) * BSZ + (c * 64 + w * 8) * 64);              \
  } while (0)

  const int fmask = (l15 & 7) << 4;
  const int bo0 = ((0 * 64) + g * 16) ^ fmask;
  const int bo1 = ((1 * 64) + g * 16) ^ fmask;
  const int aRowBase = wr * 128 + l15;
  const int bRowBase = wc * NCW + l15;

  const int NT = K >> 6;

  STAGE(0, 0);
  int buf = 0;
  for (int t = 0; t < NT; ++t) {
    const unsigned short* shAb = sh + buf * ASZ;
    const unsigned short* shBb = shB + buf * BSZ;

    asm volatile("s_waitcnt vmcnt(0)" ::: "memory");
    __builtin_amdgcn_sched_barrier(0);
    __builtin_amdgcn_s_barrier();
    if (t + 1 < NT) STAGE(buf ^ 1, (t + 1) * 64);

    bf16x8 bfr[NF][2];
#pragma unroll
    for (int n = 0; n < NF; ++n) {
      const int br = (bRowBase + n * 16) * 64;
      bfr[n][0] = *(const bf16x8*)(shBb + br + (bo0 >> 1));
      bfr[n][1] = *(const bf16x8*)(shBb + br + (bo1 >> 1));
    }
    bf16x8 afr[8][2];
#pragma unroll
    for (int m = 0; m < 8; ++m) {
      const int ar = (aRowBase + m * 16) * 64;
      afr[m][0] = *(const bf16x8*)(shAb + ar + (bo0 >> 1));
      afr[m][1] = *(const bf16x8*)(shAb + ar + (bo1 >> 1));
    }
    __builtin_amdgcn_sched_barrier(0);

#pragma unroll
    for (int p = 0; p < 4; ++p) {
#pragma unroll
      for (int n = 0; n < NF; ++n) {
        acc[2 * p][n]     = MFMA16(afr[2 * p][0],     bfr[n][0], acc[2 * p][n]);
        acc[2 * p][n]     = MFMA16(afr[2 * p][1],     bfr[n][1], acc[2 * p][n]);
        acc[2 * p + 1][n] = MFMA16(afr[2 * p + 1][0], bfr[n][0], acc[2 * p + 1][n]);
        acc[2 * p + 1][n] = MFMA16(afr[2 * p + 1][1], bfr[n][1], acc[2 * p + 1][n]);
      }
    }
    buf ^= 1;
  }
#undef STAGE

  if constexpr (EPI == 2) {
#pragma unroll
    for (int m = 0; m < 8; ++m) {
#pragma unroll
      for (int n = 0; n < NF; ++n) {
        const int col = n0 + wc * NCW + n * 16 + l15;
        const float bc = bias[col];
#pragma unroll
        for (int r = 0; r < 4; ++r) {
          const int row = m0 + wr * 128 + m * 16 + g * 4 + r;
          const size_t idx = (size_t)row * N + col;
          ((float*)Cout)[idx] = acc[m][n][r] + bc + res[idx];
        }
      }
    }
  } else {
    __builtin_amdgcn_s_barrier();
    unsigned short* ep = sh + w * (128 * NCW);
#pragma unroll
    for (int m = 0; m < 8; ++m) {
#pragma unroll
      for (int n = 0; n < NF; ++n) {
        const float bc = bias[n0 + wc * NCW + n * 16 + l15];
#pragma unroll
        for (int r = 0; r < 4; ++r) {
          float v = acc[m][n][r] + bc;
          if constexpr (EPI == 1) v = gelu_fast(v);
          ep[(m * 16 + g * 4 + r) * NCW + n * 16 + l15] = f2bf(v);
        }
      }
    }
    constexpr int CPR = NCW / 8;
#pragma unroll
    for (int j = 0; j < NCW / 4; ++j) {
      const int t = lane + j * 64;
      const int row = t / CPR, colb = (t % CPR) * 8;
      const uint4 vv = *(const uint4*)(ep + row * NCW + colb);
      unsigned short* outp = (unsigned short*)Cout +
          (size_t)(m0 + wr * 128 + row) * N + n0 + wc * NCW + colb;
      *(uint4*)outp = vv;
    }
  }
}

// ---------- NT GEMM (R16): 256x128, BK=32, 48KB LDS -> 2 blocks/CU ----------
template <int EPI>
__global__ __launch_bounds__(512, 4) void k_g32(const unsigned short* __restrict__ A,
                                                const unsigned short* __restrict__ BT,
                                                const float* __restrict__ bias,
                                                const float* __restrict__ res,
                                                void* __restrict__ Cout,
                                                int M, int N, int K) {
  constexpr int BN  = 128;
  constexpr int ASZ = 256 * 32;        // 16KB per A buffer
  constexpr int BSZ = BN * 32;         // 8KB per B buffer
  constexpr int NF  = 2;
  constexpr int NCW = 32;
  __shared__ unsigned short sh[2 * ASZ + 2 * BSZ];   // 48KB

  const int tid  = threadIdx.x;
  const int lane = tid & 63;
  const int w    = tid >> 6;
  const int wr   = w >> 2, wc = w & 3;
  const int l15  = lane & 15, g = lane >> 4;

  const int gx = gridDim.x;
  const int nwg = gx * gridDim.y;
  int lid = blockIdx.y * gx + blockIdx.x;
  lid = (lid & 7) * (nwg >> 3) + (lid >> 3);
  const int m0 = (lid / gx) * 256, n0 = (lid % gx) * BN;

  f32x4 acc[8][NF] = {};

  const int srow4 = lane >> 2;
  const int schk  = (lane & 3) ^ ((lane >> 3) & 3);
  const unsigned short* pA = A  + (size_t)(m0 + w * 32 + srow4) * K + schk * 8;
  const unsigned short* pB = BT + (size_t)(n0 + w * 16 + srow4) * K + schk * 8;
  unsigned short* shB = sh + 2 * ASZ;

#define STAGE32(buf_, kk)                                                     \
  do {                                                                        \
    gload_lds16(pA + (kk),                  sh  + (buf_) * ASZ + (w * 32) * 32);      \
    gload_lds16(pA + (size_t)16 * K + (kk), sh  + (buf_) * ASZ + (w * 32 + 16) * 32); \
    gload_lds16(pB + (kk),                  shB + (buf_) * BSZ + (w * 16) * 32);      \
  } while (0)

  const int fko = (g ^ ((l15 >> 1) & 3)) * 8;
  const int aRowBase = wr * 128 + l15;
  const int bRowBase = wc * NCW + l15;

  const int NT = K >> 5;

  STAGE32(0, 0);
  int buf = 0;
  for (int t = 0; t < NT; ++t) {
    const unsigned short* shAb = sh + buf * ASZ;
    const unsigned short* shBb = shB + buf * BSZ;

    asm volatile("s_waitcnt vmcnt(0)" ::: "memory");
    __builtin_amdgcn_sched_barrier(0);
    __builtin_amdgcn_s_barrier();
    if (t + 1 < NT) STAGE32(buf ^ 1, (t + 1) * 32);

    bf16x8 bfr[NF];
#pragma unroll
    for (int n = 0; n < NF; ++n)
      bfr[n] = *(const bf16x8*)(shBb + (bRowBase + n * 16) * 32 + fko);
    bf16x8 afr[8];
#pragma unroll
    for (int m = 0; m < 8; ++m)
      afr[m] = *(const bf16x8*)(shAb + (aRowBase + m * 16) * 32 + fko);
    __builtin_amdgcn_sched_barrier(0);

#pragma unroll
    for (int p = 0; p < 4; ++p) {
#pragma unroll
      for (int n = 0; n < NF; ++n) {
        acc[2 * p][n]     = MFMA16(afr[2 * p],     bfr[n], acc[2 * p][n]);
        acc[2 * p + 1][n] = MFMA16(afr[2 * p + 1], bfr[n], acc[2 * p + 1][n]);
      }
    }
    buf ^= 1;
  }
#undef STAGE32

  if constexpr (EPI == 2) {
#pragma unroll
    for (int m = 0; m < 8; ++m) {
#pragma unroll
      for (int n = 0; n < NF; ++n) {
        const int col = n0 + wc * NCW + n * 16 + l15;
        const float bc = bias[col];
#pragma unroll
        for (int r = 0; r < 4; ++r) {
          const int row = m0 + wr * 128 + m * 16 + g * 4 + r;
          const size_t idx = (size_t)row * N + col;
          ((float*)Cout)[idx] = acc[m][n][r] + bc + res[idx];
        }
      }
    }
  } else {
    // bf16 out via per-wave LDS tile in two 64-row halves (32KB of 48KB)
    __builtin_amdgcn_s_barrier();
    unsigned short* ep = sh + w * (64 * NCW);
#pragma unroll
    for (int hm = 0; hm < 2; ++hm) {
#pragma unroll
      for (int m = 0; m < 4; ++m) {
        const int mm = hm * 4 + m;
#pragma unroll
        for (int n = 0; n < NF; ++n) {
          const float bc = bias[n0 + wc * NCW + n * 16 + l15];
#pragma unroll
          for (int r = 0; r < 4; ++r) {
            float v = acc[mm][n][r] + bc;
            if constexpr (EPI == 1) v = gelu_fast(v);
            ep[(m * 16 + g * 4 + r) * NCW + n * 16 + l15] = f2bf(v);
          }
        }
      }
#pragma unroll
      for (int j = 0; j < 4; ++j) {
        const int t = lane + j * 64;
        const int row = t >> 2, colb = (t & 3) * 8;
        const uint4 vv = *(const uint4*)(ep + row * NCW + colb);
        unsigned short* outp = (unsigned short*)Cout +
            (size_t)(m0 + wr * 128 + hm * 64 + row) * N + n0 + wc * NCW + colb;
        *(uint4*)outp = vv;
      }
    }
  }
}

// ---------- V transpose: qkv (M x 3072) V-columns -> vT [nh][64][1024] bf16 ----------
__global__ __launch_bounds__(256) void k_vt(const unsigned short* __restrict__ qkv,
                                            unsigned short* __restrict__ vT) {
  __shared__ unsigned short t[64][72];
  const int nh = blockIdx.y;
  const int nb = nh >> 4, h = nh & 15;
  const int l0 = blockIdx.x * 64;
  const int tx = threadIdx.x & 7;
  const int ty = threadIdx.x >> 3;
  const unsigned short* src = qkv + (size_t)(nb * SEQ + l0) * 3072 + 2048 + h * DHEAD;
#pragma unroll
  for (int j = 0; j < 2; ++j)
    *(uint4*)(&t[ty + j * 32][tx * 8]) =
        *(const uint4*)(&src[(size_t)(ty + j * 32) * 3072 + tx * 8]);
  __syncthreads();
  unsigned short* dst = vT + (size_t)nh * DHEAD * SEQ + l0;
#pragma unroll
  for (int j = 0; j < 2; ++j) {
    const int d = ty + j * 32;
    ushort4 a, b;
    a.x = t[tx * 8 + 0][d]; a.y = t[tx * 8 + 1][d];
    a.z = t[tx * 8 + 2][d]; a.w = t[tx * 8 + 3][d];
    b.x = t[tx * 8 + 4][d]; b.y = t[tx * 8 + 5][d];
    b.z = t[tx * 8 + 6][d]; b.w = t[tx * 8 + 7][d];
    *(ushort4*)(&dst[(size_t)d * SEQ + tx * 8])     = a;
    *(ushort4*)(&dst[(size_t)d * SEQ + tx * 8 + 4]) = b;
  }
}

// ---------- flash attention, LDS-staged K/V, swapped QK^T ----------
#define SOFTMAX_GROUP(S, gq)                                                       \
  {                                                                                \
    float mx = -INFINITY;                                                          \
    _Pragma("unroll") for (int c = 0; c < 4; ++c)                                  \
      _Pragma("unroll") for (int r = 0; r < 4; ++r)                                \
        mx = fmaxf(mx, S[c][r]);                                                   \
    mx = fmaxf(mx, __shfl_xor(mx, 16));                                            \
    mx = fmaxf(mx, __shfl_xor(mx, 32));                                            \
    const float mnew = fmaxf(m_run[gq], mx);                                       \
    const float sc = __expf(0.125f * (m_run[gq] - mnew));                          \
    m_run[gq] = mnew;                                                              \
    float ts = 0.0f;                                                               \
    _Pragma("unroll") for (int c = 0; c < 4; ++c) {                                \
      const float p0 = __expf(0.125f * (S[c][0] - mnew));                          \
      const float p1 = __expf(0.125f * (S[c][1] - mnew));                          \
      const float p2 = __expf(0.125f * (S[c][2] - mnew));                          \
      const float p3 = __expf(0.125f * (S[c][3] - mnew));                          \
      ts += (p0 + p1) + (p2 + p3);                                                 \
      const unsigned int lo = (unsigned int)f2bf(p0) | ((unsigned int)f2bf(p1) << 16); \
      const unsigned int hi = (unsigned int)f2bf(p2) | ((unsigned int)f2bf(p3) << 16); \
      *(uint2*)(&P_lds[w][((gq) * 16 + l15) * 72 + c * 16 + g * 4]) = make_uint2(lo, hi); \
    }                                                                              \
    ts += __shfl_xor(ts, 16);                                                      \
    ts += __shfl_xor(ts, 32);                                                      \
    s_run[gq] = s_run[gq] * sc + ts;                                               \
    const float scr0 = __shfl(sc, g * 4 + 0), scr1 = __shfl(sc, g * 4 + 1);        \
    const float scr2 = __shfl(sc, g * 4 + 2), scr3 = __shfl(sc, g * 4 + 3);        \
    _Pragma("unroll") for (int dt = 0; dt < 4; ++dt) {                             \
      o[gq][dt][0] *= scr0; o[gq][dt][1] *= scr1;                                  \
      o[gq][dt][2] *= scr2; o[gq][dt][3] *= scr3;                                  \
    }                                                                              \
  }

__global__ __launch_bounds__(256, 4) void k_attn(const unsigned short* __restrict__ qkv,
                                                 const unsigned short* __restrict__ vT,
                                                 unsigned short* __restrict__ outp) {
  __shared__ unsigned short Ks[64 * 64];
  __shared__ unsigned short Vs[64 * 64];
  __shared__ unsigned short P_lds[4][32 * 72];
  const int tid  = threadIdx.x;
  const int lane = tid & 63;
  const int w    = tid >> 6;
  const int l15  = lane & 15, g = lane >> 4;
  const int nh = blockIdx.y;
  const int nb = nh >> 4, h = nh & 15;
  const int q0 = blockIdx.x * 128 + w * 32;
  const size_t RS = 3 * HID;

  const unsigned short* Qp = qkv + (size_t)(nb * SEQ + q0) * RS + h * DHEAD;
  const unsigned short* Kg = qkv + (size_t)(nb * SEQ) * RS + HID + h * DHEAD;
  const unsigned short* Vg = vT + (size_t)nh * DHEAD * SEQ;

  const int L0 = tid * 32, L1 = L0 + 16;
  const int kr0 = L0 >> 7, kc0 = (L0 & 127) ^ ((kr0 & 7) << 4);
  const int kr1 = L1 >> 7, kc1 = (L1 & 127) ^ ((kr1 & 7) << 4);

  bf16x8 aq[2][2];
#pragma unroll
  for (int gq = 0; gq < 2; ++gq)
#pragma unroll
    for (int t = 0; t < 2; ++t)
      aq[gq][t] = *(const bf16x8*)(&Qp[(size_t)(gq * 16 + l15) * RS + t * 32 + g * 8]);

  f32x4 o[2][4] = {};
  float m_run[2] = {-INFINITY, -INFINITY};
  float s_run[2] = {0.0f, 0.0f};

  uint4 rk0, rk1, rv0, rv1;
  rk0 = *(const uint4*)(Kg + (size_t)kr0 * RS + (kc0 >> 1));
  rk1 = *(const uint4*)(Kg + (size_t)kr1 * RS + (kc1 >> 1));
  rv0 = *(const uint4*)(Vg + (size_t)kr0 * SEQ + (kc0 >> 1));
  rv1 = *(const uint4*)(Vg + (size_t)kr1 * SEQ + (kc1 >> 1));
  *(uint4*)(&Ks[tid * 16])     = rk0;
  *(uint4*)(&Ks[tid * 16 + 8]) = rk1;
  *(uint4*)(&Vs[tid * 16])     = rv0;
  *(uint4*)(&Vs[tid * 16 + 8]) = rv1;
  __syncthreads();

  const int sw = (l15 & 7) << 4;

  for (int t16 = 0; t16 < 16; ++t16) {
    if (t16 < 15) {
      const int kb = (t16 + 1) * 64;
      rk0 = *(const uint4*)(Kg + (size_t)(kb + kr0) * RS + (kc0 >> 1));
      rk1 = *(const uint4*)(Kg + (size_t)(kb + kr1) * RS + (kc1 >> 1));
      rv0 = *(const uint4*)(Vg + (size_t)kr0 * SEQ + kb + (kc0 >> 1));
      rv1 = *(const uint4*)(Vg + (size_t)kr1 * SEQ + kb + (kc1 >> 1));
    }

    f32x4 S0[4], S1[4];
#pragma unroll
    for (int c = 0; c < 4; ++c) {
      const int krow = c * 16 + l15;
      const bf16x8 k0 = *(const bf16x8*)(&Ks[krow * 64 + ((( 0 + g * 16) ^ sw) >> 1)]);
      const bf16x8 k1 = *(const bf16x8*)(&Ks[krow * 64 + (((64 + g * 16) ^ sw) >> 1)]);
      f32x4 a = {};
      a = MFMA16(k0, aq[0][0], a);
      a = MFMA16(k1, aq[0][1], a);
      S0[c] = a;
      f32x4 b = {};
      b = MFMA16(k0, aq[1][0], b);
      b = MFMA16(k1, aq[1][1], b);
      S1[c] = b;
    }

    SOFTMAX_GROUP(S0, 0)
    SOFTMAX_GROUP(S1, 1)

    bf16x8 pa[2][2];
#pragma unroll
    for (int gq = 0; gq < 2; ++gq)
#pragma unroll
      for (int th = 0; th < 2; ++th)
        pa[gq][th] = *(const bf16x8*)(&P_lds[w][(gq * 16 + l15) * 72 + th * 32 + g * 8]);
#pragma unroll
    for (int dt = 0; dt < 4; ++dt) {
      const int vrow = dt * 16 + l15;
      const bf16x8 v0 = *(const bf16x8*)(&Vs[vrow * 64 + ((( 0 + g * 16) ^ sw) >> 1)]);
      const bf16x8 v1 = *(const bf16x8*)(&Vs[vrow * 64 + (((64 + g * 16) ^ sw) >> 1)]);
      o[0][dt] = MFMA16(pa[0][0], v0, o[0][dt]);
      o[0][dt] = MFMA16(pa[0][1], v1, o[0][dt]);
      o[1][dt] = MFMA16(pa[1][0], v0, o[1][dt]);
      o[1][dt] = MFMA16(pa[1][1], v1, o[1][dt]);
    }
    __syncthreads();
    if (t16 < 15) {
      *(uint4*)(&Ks[tid * 16])     = rk0;
      *(uint4*)(&Ks[tid * 16 + 8]) = rk1;
      *(uint4*)(&Vs[tid * 16])     = rv0;
      *(uint4*)(&Vs[tid * 16 + 8]) = rv1;
      __syncthreads();
    }
  }

#pragma unroll
  for (int gq = 0; gq < 2; ++gq) {
    float sr[4];
#pragma unroll
    for (int r = 0; r < 4; ++r) sr[r] = 1.0f / __shfl(s_run[gq], g * 4 + r);
#pragma unroll
    for (int dt = 0; dt < 4; ++dt)
#pragma unroll
      for (int r = 0; r < 4; ++r)
        outp[(size_t)(nb * SEQ + q0 + gq * 16 + g * 4 + r) * HID + h * DHEAD + dt * 16 + l15] =
            f2bf(o[gq][dt][r] * sr[r]);
  }
}

extern "C" void kernel_launch(void* const* d_in, const int* in_sizes, int n_in,
                              void* d_out, int out_size, void* d_ws, size_t ws_size,
                              hipStream_t stream) {
  const float* x    = (const float*)d_in[0];
  const float* ln0g = (const float*)d_in[1];
  const float* ln0b = (const float*)d_in[2];
  const float* wq   = (const float*)d_in[3];
  const float* bq   = (const float*)d_in[4];
  const float* wk   = (const float*)d_in[5];
  const float* bk   = (const float*)d_in[6];
  const float* wv   = (const float*)d_in[7];
  const float* bv   = (const float*)d_in[8];
  const float* wo   = (const float*)d_in[9];
  const float* bo   = (const float*)d_in[10];
  const float* ln1g = (const float*)d_in[11];
  const float* ln1b = (const float*)d_in[12];
  const float* w1   = (const float*)d_in[13];
  const float* b1   = (const float*)d_in[14];
  const float* w2   = (const float*)d_in[15];
  const float* b2   = (const float*)d_in[16];
  float* out = (float*)d_out;

  char* ws = (char*)d_ws;
  unsigned short* qkvT = (unsigned short*)(ws + 0);          // 3072x1024 bf16   (6 MB)
  unsigned short* woT  = (unsigned short*)(ws + 6291456);    // 1024x1024 bf16   (2 MB)
  unsigned short* w1T  = (unsigned short*)(ws + 8388608);    // 4096x1024 bf16   (8 MB)
  unsigned short* w2T  = (unsigned short*)(ws + 16777216);   // 1024x4096 bf16   (8 MB)
  float*          bqkv = (float*)(ws + 25165824);            // 3072 f32
  unsigned short* ybuf = (unsigned short*)(ws + 25178112);   // 8192x1024 bf16   (16 MB)
  unsigned short* qkv  = (unsigned short*)(ws + 41955328);   // 8192x3072 bf16   (48 MB)
  unsigned short* att  = (unsigned short*)(ws + 92286976);   // 8192x1024 bf16   (16 MB)
  unsigned short* hbuf = qkv;   // 8192x4096 bf16 (64 MB) overlays qkv+att (both dead)
  unsigned short* vT   = ybuf;  // 128x64x1024 bf16 (16 MB) overlays ybuf

  const int M = NBATCH * SEQ;  // 8192

  // merged weight prep: ONE launch
  k_prep<<<dim3(12300), 256, 0, stream>>>(wq, wk, wv, wo, w1, w2, bq, bk, bv,
                                          qkvT, woT, w1T, w2T, bqkv);

  // LN0 -> y
  k_ln<<<dim3(M), 256, 0, stream>>>(x, ln0g, ln0b, ybuf);
  // QKV (K=1024): R15 config, BN=256 BK=64, 12x32 blocks
  k_gemm<0, 256><<<dim3(12, 32), 512, 0, stream>>>(ybuf, qkvT, bqkv, nullptr, (void*)qkv, M, 3 * HID, HID);
  // V^T materialization
  k_vt<<<dim3(16, 128), 256, 0, stream>>>(qkv, vT);
  // attention
  k_attn<<<dim3(8, 128), 256, 0, stream>>>(qkv, vT, att);
  // x1 = x + att @ wo + bo: R15 config, BN=128 BK=64
  k_gemm<2, 128><<<dim3(8, 32), 512, 0, stream>>>(att, woT, bo, x, (void*)out, M, HID, HID);
  // LN1 -> y
  k_ln<<<dim3(M), 256, 0, stream>>>(out, ln1g, ln1b, ybuf);
  // h = gelu(y @ w1 + b1): R16's BK=32 2-blocks/CU kernel (measured 110us)
  k_g32<1><<<dim3(32, 32), 512, 0, stream>>>(ybuf, w1T, b1, nullptr, (void*)hbuf, M, MLPD, HID);
  // out = d_out + h @ w2 + b2 (K=4096): R15 config, BN=128 BK=64
  k_gemm<2, 128><<<dim3(8, 32), 512, 0, stream>>>(hbuf, w2T, b2, out, (void*)out, M, HID, MLPD);
}